// Round 13
// baseline (257.776 us; speedup 1.0000x reference)
//
#include <hip/hip_runtime.h>
#include <math.h>

#define H_DIM 1024
#define NHEAD 16
#define DHEAD 64
#define T_W 1024
#define T_E 128
#define T_T 1152
#define BATCH 4

typedef __attribute__((ext_vector_type(8))) short s8b;   // 8 bf16 (4 VGPRs)
typedef __attribute__((ext_vector_type(4))) short s4b;   // 4 bf16 (8 B)
typedef __attribute__((ext_vector_type(4))) float f32x4;
typedef __attribute__((ext_vector_type(16))) float f32x16;
typedef __attribute__((ext_vector_type(4))) unsigned int u32x4;

#define LOG2E 1.44269504088896f

__device__ __forceinline__ unsigned short f2bf(float f) {
    unsigned int u = __float_as_uint(f);
    u = (u + 0x7fffu + ((u >> 16) & 1u)) >> 16;   // RNE
    return (unsigned short)u;
}

__device__ __forceinline__ unsigned int pk_bf16(float a, float b) {
#if __has_builtin(__builtin_amdgcn_cvt_pk_bf16_f32)
    typedef __bf16 bf2 __attribute__((ext_vector_type(2)));
    bf2 r = __builtin_amdgcn_cvt_pk_bf16_f32(a, b);
    return __builtin_bit_cast(unsigned int, r);
#else
    return (unsigned int)f2bf(a) | ((unsigned int)f2bf(b) << 16);
#endif
}

__device__ __forceinline__ float exp2f_fast(float x) {
#if __has_builtin(__builtin_amdgcn_exp2f)
    return __builtin_amdgcn_exp2f(x);
#else
    return exp2f(x);
#endif
}

__device__ __forceinline__ void gld_lds16(const void* g, void* l) {
    __builtin_amdgcn_global_load_lds(
        (const __attribute__((address_space(1))) unsigned int*)g,
        (__attribute__((address_space(3))) unsigned int*)l, 16, 0, 0);
}

// ------------- fused prep: bf16 converts + mask prescale + 8 weight transposes
struct WPtrs { const float* w[8]; };
__global__ __launch_bounds__(256) void k_prep2(
    const float* __restrict__ word, const float* __restrict__ ent,
    const float* __restrict__ qp, const float* __restrict__ mask,
    unsigned short* __restrict__ word_bf, unsigned short* __restrict__ pe_bf,
    unsigned short* __restrict__ ent_bf, float* __restrict__ mask2,
    WPtrs ws, unsigned short* __restrict__ Wt)
{
    const int bid = blockIdx.x;
    if (bid < 4096) {
        int i = bid * 256 + threadIdx.x;
        float4 v = ((const float4*)word)[i];
        *(uint2*)(word_bf + (size_t)i * 4) =
            make_uint2(pk_bf16(v.x, v.y), pk_bf16(v.z, v.w));
    } else if (bid < 4608) {
        int i = (bid - 4096) * 256 + threadIdx.x;
        float4 a = ((const float4*)ent)[i];
        float4 b = ((const float4*)qp)[i];
        *(uint2*)(ent_bf + (size_t)i * 4) =
            make_uint2(pk_bf16(a.x, a.y), pk_bf16(a.z, a.w));
        *(uint2*)(pe_bf + (size_t)i * 4) =
            make_uint2(pk_bf16((a.x + b.x) * 0.5f, (a.y + b.y) * 0.5f),
                       pk_bf16((a.z + b.z) * 0.5f, (a.w + b.w) * 0.5f));
    } else if (bid < 4626) {
        int i = (bid - 4608) * 256 + threadIdx.x;
        if (i < BATCH * T_T) mask2[i] = mask[i] * LOG2E;
    } else {
        __shared__ float tile[32][33];
        const int id = bid - 4626;
        const int z = id >> 10, rem = id & 1023;
        const int kb = (rem >> 5) * 32, nb = (rem & 31) * 32;
        const float* src = ws.w[z];
        unsigned short* dst = Wt + (size_t)z * H_DIM * H_DIM;
        const int tx = threadIdx.x & 31, ty = threadIdx.x >> 5;
        #pragma unroll
        for (int i = 0; i < 4; i++)
            tile[ty * 4 + i][tx] = src[(size_t)(kb + ty * 4 + i) * H_DIM + nb + tx];
        __syncthreads();
        #pragma unroll
        for (int i = 0; i < 4; i++)
            dst[(size_t)(nb + ty * 4 + i) * H_DIM + kb + tx] =
                f2bf(tile[tx][ty * 4 + i]);
    }
}

struct B6 { const float* b[6]; };
struct O3p { void* o[3]; };

// =================== 64x128 BK=64 swizzled-LDS MFMA GEMM core ================
// LDS double-buffered, T4 counted-vmcnt loop (R10/R12-verified, neutral-kept).

#define STAGE_GEMM(k0, base)                                                     \
    {                                                                            \
        gld_lds16(gA + (k0), &sm[(base) + t * 8]);                               \
        gld_lds16(gA + (size_t)32 * H_DIM + (k0), &sm[(base) + 2048 + t * 8]);   \
        gld_lds16(gB + (k0), &sm[(base) + 4096 + t * 8]);                        \
        gld_lds16(gB + (size_t)32 * H_DIM + (k0), &sm[(base) + 6144 + t * 8]);   \
        gld_lds16(gB + (size_t)64 * H_DIM + (k0), &sm[(base) + 8192 + t * 8]);   \
        gld_lds16(gB + (size_t)96 * H_DIM + (k0), &sm[(base) + 10240 + t * 8]);  \
    }

#define GEMM_KLOOP                                                               \
    STAGE_GEMM(0, 0)                                                             \
    int base = 0;                                                                \
    for (int k0 = 0; k0 < H_DIM; k0 += 64) {                                     \
        __builtin_amdgcn_s_barrier();            /* (A) buf^1 reusable */        \
        if (k0 + 64 < H_DIM) {                                                   \
            STAGE_GEMM(k0 + 64, base ^ 12288)                                    \
            asm volatile("s_waitcnt vmcnt(6)" ::: "memory");                     \
        } else {                                                                 \
            asm volatile("s_waitcnt vmcnt(0)" ::: "memory");                     \
        }                                                                        \
        __builtin_amdgcn_s_barrier();            /* (B) tile-t LDS ready */      \
        __builtin_amdgcn_sched_barrier(0);                                       \
        _Pragma("unroll")                                                        \
        for (int kk = 0; kk < 2; kk++) {                                         \
            s8b af[2], bfr[4];                                                   \
            _Pragma("unroll")                                                    \
            for (int mt = 0; mt < 2; mt++) {                                     \
                const int r = wm * 32 + mt * 16 + col;                           \
                af[mt] = *(const s8b*)&sm[base + r * 64 +                        \
                                          (((kk * 4 + quad) ^ (r & 7)) * 8)];    \
            }                                                                    \
            _Pragma("unroll")                                                    \
            for (int nt = 0; nt < 4; nt++) {                                     \
                const int r = wn * 64 + nt * 16 + col;                           \
                bfr[nt] = *(const s8b*)&sm[base + 4096 + r * 64 +                \
                                           (((kk * 4 + quad) ^ (r & 7)) * 8)];   \
            }                                                                    \
            __builtin_amdgcn_s_setprio(1);                                       \
            _Pragma("unroll")                                                    \
            for (int mt = 0; mt < 2; mt++)                                       \
                _Pragma("unroll")                                                \
                for (int nt = 0; nt < 4; nt++)                                   \
                    acc[mt][nt] = __builtin_amdgcn_mfma_f32_16x16x32_bf16(       \
                        af[mt], bfr[nt], acc[mt][nt], 0, 0, 0);                  \
            __builtin_amdgcn_s_setprio(0);                                       \
        }                                                                        \
        base ^= 12288;                                                           \
    }

// ---------------------- QKV projections, word+entity in ONE launch
__global__ __launch_bounds__(256) void k_proj(
    const unsigned short* __restrict__ word_bf,
    const unsigned short* __restrict__ pe_bf,
    const unsigned short* __restrict__ ent_bf,
    const unsigned short* __restrict__ Wtbase, B6 biases, O3p outs)
{
    const int z = blockIdx.z;
    const bool isw = blockIdx.y < 64;
    const int Tseq = isw ? T_W : T_E;
    const int toff = isw ? 0 : T_W;
    const int m0 = (isw ? blockIdx.y : (blockIdx.y - 64)) * 64;
    const unsigned short* A = isw ? word_bf : (z == 2 ? ent_bf : pe_bf);
    const int wi = (isw ? 0 : 3) + z;
    const unsigned short* B = Wtbase + (size_t)wi * H_DIM * H_DIM;
    const float* bias = biases.b[wi];
    void* outp = outs.o[z];

    __shared__ unsigned short sm[24576];
    const int t = threadIdx.x;
    const int w = t >> 6, lane = t & 63;
    const int col = lane & 15, quad = lane >> 4;
    const int n0 = blockIdx.x * 128;
    const int wm = w & 1, wn = w >> 1;

    f32x4 acc[2][4] = {};

    const int rs = t >> 3;                       // staging row within pass
    const int gch = (t & 7) ^ (rs & 7);          // global chunk for this thread
    const unsigned short* gA = A + (size_t)(m0 + rs) * H_DIM + gch * 8;
    const unsigned short* gB = B + (size_t)(n0 + rs) * H_DIM + gch * 8;

    GEMM_KLOOP

    #pragma unroll
    for (int mt = 0; mt < 2; mt++) {
        const int mg = m0 + wm * 32 + mt * 16 + quad * 4;
        const int b = mg / Tseq, tt = toff + (mg % Tseq);
        #pragma unroll
        for (int nt = 0; nt < 4; nt++) {
            const int ng = n0 + wn * 64 + nt * 16 + col;
            f32x4 c = acc[mt][nt];
            const float bn = bias[ng];
            if (z < 2) {
                unsigned short* out = (unsigned short*)outp;
                #pragma unroll
                for (int r = 0; r < 4; r++)
                    out[((size_t)b * T_T + tt + r) * H_DIM + ng] = f2bf(c[r] + bn);
            } else {
                unsigned short* out = (unsigned short*)outp;
                *(uint2*)(out + ((size_t)b * H_DIM + ng) * T_T + tt) =
                    make_uint2(pk_bf16(c[0] + bn, c[1] + bn),
                               pk_bf16(c[2] + bn, c[3] + bn));
            }
        }
    }
}

// ---------------------- output GEMMs (word + entity), 576 blocks, 64x128 tile
__global__ __launch_bounds__(256) void k_gemm_out(
    const unsigned short* __restrict__ ctx,
    const unsigned short* __restrict__ Wt_o, const unsigned short* __restrict__ Wt_eo,
    const float* __restrict__ bo, const float* __restrict__ beo,
    const float* __restrict__ word, const float* __restrict__ ent,
    float* __restrict__ out_word, float* __restrict__ out_ent)
{
    const int blk = blockIdx.x;
    const bool is_word = blk < 512;
    const int lb = is_word ? blk : blk - 512;
    const int m0 = (lb >> 3) * 64, n0 = (lb & 7) * 128;
    const unsigned short* B = is_word ? Wt_o : Wt_eo;
    const float* bias = is_word ? bo : beo;
    const float* resid = is_word ? word : ent;
    float* out = is_word ? out_word : out_ent;
    const int Tseq = is_word ? T_W : T_E;
    const int toff = is_word ? 0 : T_W;

    __shared__ unsigned short sm[24576];
    const int t = threadIdx.x;
    const int w = t >> 6, lane = t & 63;
    const int col = lane & 15, quad = lane >> 4;
    const int wm = w & 1, wn = w >> 1;

    f32x4 acc[2][4] = {};

    const int rs = t >> 3;
    const int gch = (t & 7) ^ (rs & 7);
    // ctx row remap: 64-row tile stays within one batch (m0 mult of 64)
    const size_t arow = (size_t)(m0 / Tseq) * T_T + toff + (m0 % Tseq) + rs;
    const unsigned short* gA = ctx + arow * H_DIM + gch * 8;
    const unsigned short* gB = B + (size_t)(n0 + rs) * H_DIM + gch * 8;

    GEMM_KLOOP

    #pragma unroll
    for (int mt = 0; mt < 2; mt++) {
        const int mg = m0 + wm * 32 + mt * 16 + quad * 4;
        #pragma unroll
        for (int nt = 0; nt < 4; nt++) {
            const int ng = n0 + wn * 64 + nt * 16 + col;
            f32x4 c = acc[mt][nt];
            const float bn = bias[ng];
            #pragma unroll
            for (int r = 0; r < 4; r++) {
                const size_t idx = (size_t)(mg + r) * H_DIM + ng;
                out[idx] = c[r] + bn + resid[idx];
            }
        }
    }
}

// ------------------------------------------- cooperative S^T flash attention
// R13: 32x32 MFMA restructure to cut LDS traffic (the measured-inferred
// bound: 18 b128 reads/wave-tile x 8 waves = 176 KB/block-tile ~ 35 TB/s
// ~60% of the 69 TB/s LDS ceiling). New: 4 waves x 32 q-rows (same 128
// q/block, same 576-block grid + XCD swizzle + counted-vmcnt skeleton).
// QK^T = mfma_32x32x16(K, Q): C col=lane&31=q, row k=(reg&3)+8*(reg>>2)+
// 4*(lane>>5) [guide-verified m74/m101]. P->PV B-operand fully in-register:
// cvt_pk pairs + shfl_xor(.,32) half-exchange (T12 pattern) -- sP LDS
// round-trip eliminated. PV = mfma_32x32x16(V^T, P), V^T staged as before.
// Per block-tile LDS: 176 KB -> ~80 KB (16 b128/wave x 4 waves + exchange).
// A/B frag layout (extrapolated from verified 16x16x32): row=l&31,
// k=(l>>5)*8+j. Swizzle: chunk c of row r at slot c^(r&7) (unchanged).
__global__ __launch_bounds__(256) void k_attn(
    const unsigned short* __restrict__ q, const unsigned short* __restrict__ k,
    const unsigned short* __restrict__ vt, const float* __restrict__ mask2,
    unsigned short* __restrict__ ctx)
{
    const int tid = threadIdx.x;
    const int w = tid >> 6, lane = tid & 63;
    const int qc = lane & 31, h = lane >> 5;
    const int bid = blockIdx.x;
    const int bh = ((bid & 7) << 3) | ((bid >> 3) & 7);   // bijective over 576
    const int q0 = (bid >> 6) * 128;
    const int b = bh >> 4, hd = bh & 15;

    __shared__ unsigned short sK[2][64 * 64];
    __shared__ unsigned short sV[2][64 * 64];

    const unsigned short* qp = q + ((size_t)b * T_T + q0 + w * 32) * H_DIM + hd * DHEAD;
    const unsigned short* kp = k + (size_t)b * T_T * H_DIM + hd * DHEAD;
    const unsigned short* vp = vt + ((size_t)b * H_DIM + hd * DHEAD) * T_T;
    const float* mp = mask2 + (size_t)b * T_T;

    // Q fragments (B-operand): lane supplies Q[q=qc][d = ds*16 + h*8 + j]
    s8b qf[4];
    #pragma unroll
    for (int ds = 0; ds < 4; ds++)
        qf[ds] = *(const s8b*)(qp + (size_t)qc * H_DIM + ds * 16 + h * 8);

    // staging: 256 threads x 2 chunks each per buffer (512 chunks = 64x64 bf16)
    const int r1 = tid >> 3;
    const int c1 = (tid & 7) ^ (r1 & 7);

    const float SC2 = 0.125f * LOG2E;

    f32x16 O[2] = {};
    float l_part = 0.f;

    #define PREFETCH(J0, BUF)                                                        \
        {                                                                            \
            gld_lds16(kp + (size_t)((J0) + r1) * H_DIM + c1 * 8,                     \
                      &sK[BUF][0] + tid * 8);                                        \
            gld_lds16(kp + (size_t)((J0) + 32 + r1) * H_DIM + c1 * 8,                \
                      &sK[BUF][0] + 2048 + tid * 8);                                 \
            gld_lds16(vp + (size_t)r1 * T_T + (J0) + c1 * 8,                         \
                      &sV[BUF][0] + tid * 8);                                        \
            gld_lds16(vp + (size_t)(r1 + 32) * T_T + (J0) + c1 * 8,                  \
                      &sV[BUF][0] + 2048 + tid * 8);                                 \
        }

    PREFETCH(0, 0)
    for (int it = 0; it < 18; it++) {
        const int j0 = it * 64;
        // (A) all waves done computing tile it-1 -> buf (it+1)&1 reusable
        __builtin_amdgcn_s_barrier();
        // mask loads FIRST (older than prefetch in vmcnt order):
        // lane needs m[k] at k = kb*32 + 8g + 4h + {0..3}
        float4 mr[8];
        #pragma unroll
        for (int kb = 0; kb < 2; kb++)
            #pragma unroll
            for (int g = 0; g < 4; g++)
                mr[kb * 4 + g] =
                    *(const float4*)(mp + j0 + kb * 32 + 8 * g + 4 * h);
        __builtin_amdgcn_sched_barrier(0);   // pin: mask before prefetch
        if (it < 17) {
            PREFETCH(j0 + 64, (it + 1) & 1)
            // outstanding: tile-it K/V (4, oldest) + mask (8) + prefetch (4)
            asm volatile("s_waitcnt vmcnt(12)" ::: "memory");
        } else {
            // outstanding: tile-17 K/V (4, oldest) + mask (8)
            asm volatile("s_waitcnt vmcnt(8)" ::: "memory");
        }
        // (B) every wave's tile-it loads have landed in LDS
        __builtin_amdgcn_s_barrier();
        __builtin_amdgcn_sched_barrier(0);

        const unsigned short* K0 = &sK[it & 1][0];
        const unsigned short* V0 = &sV[it & 1][0];

        #pragma unroll
        for (int kb = 0; kb < 2; kb++) {
            // ---- QK^T: z[reg] = S[k = kb*32 + (reg&3)+8*(reg>>2)+4h][q=qc]
            f32x16 z = {};
            __builtin_amdgcn_s_setprio(1);
            #pragma unroll
            for (int ds = 0; ds < 4; ds++) {
                const int r = kb * 32 + qc;
                s8b kf = *(const s8b*)&K0[r * 64 +
                                          (((ds * 2 + h) ^ (r & 7)) * 8)];
                z = __builtin_amdgcn_mfma_f32_32x32x16_bf16(kf, qf[ds], z, 0, 0, 0);
            }
            __builtin_amdgcn_s_setprio(0);

            // ---- softmax numerator
            float p[16];
            #pragma unroll
            for (int g = 0; g < 4; g++) {
                float mv[4] = {mr[kb * 4 + g].x, mr[kb * 4 + g].y,
                               mr[kb * 4 + g].z, mr[kb * 4 + g].w};
                #pragma unroll
                for (int r2 = 0; r2 < 4; r2++) {
                    float pe = exp2f_fast(fmaf(z[g * 4 + r2], SC2, mv[r2]));
                    p[g * 4 + r2] = pe;
                    l_part += pe;
                }
            }

            // ---- P -> PV B-fragments, in-register (no LDS):
            // within-kb index x = (reg&3)+8*(reg>>2)+4h'; B-frag for 16-k
            // chunk cl needs x = cl*16 + h*8 + j. Words from cvt_pk pairs +
            // half-exchange across lane^32.
            unsigned pw[8];
            #pragma unroll
            for (int i = 0; i < 8; i++)
                pw[i] = pk_bf16(p[2 * i], p[2 * i + 1]);
            s8b pb[2];
            #pragma unroll
            for (int cl = 0; cl < 2; cl++) {
                unsigned a  = pw[cl * 4 + 0], bq = pw[cl * 4 + 1];
                unsigned c  = pw[cl * 4 + 2], d  = pw[cl * 4 + 3];
                unsigned sa = (unsigned)__shfl_xor((int)a, 32);
                unsigned sb = (unsigned)__shfl_xor((int)bq, 32);
                unsigned sc = (unsigned)__shfl_xor((int)c, 32);
                unsigned sd = (unsigned)__shfl_xor((int)d, 32);
                unsigned w0 = h ? sc : a;    // j {0,1}
                unsigned w1 = h ? sd : bq;   // j {2,3}
                unsigned w2 = h ? c  : sa;   // j {4,5}
                unsigned w3 = h ? d  : sb;   // j {6,7}
                u32x4 uu = {w0, w1, w2, w3};
                pb[cl] = __builtin_bit_cast(s8b, uu);
            }

            // ---- PV: O[db] += V^T-frag x P-frag over chunks kc = kb*2+cl
            __builtin_amdgcn_s_setprio(1);
            #pragma unroll
            for (int db = 0; db < 2; db++) {
                #pragma unroll
                for (int cl = 0; cl < 2; cl++) {
                    const int kc = kb * 2 + cl;
                    const int r = db * 32 + qc;
                    s8b vf = *(const s8b*)&V0[r * 64 +
                                              (((kc * 2 + h) ^ (r & 7)) * 8)];
                    O[db] = __builtin_amdgcn_mfma_f32_32x32x16_bf16(
                        vf, pb[cl], O[db], 0, 0, 0);
                }
            }
            __builtin_amdgcn_s_setprio(0);
        }
    }
    #undef PREFETCH

    // denominator: lane holds half (its h) of the k-sum for q=qc
    float l_c = l_part + __shfl_xor(l_part, 32);
    const float inv = 1.f / l_c;

    // O[db][reg] = O[d = db*32 + (reg&3)+8*(reg>>2)+4h][q=qc]
    unsigned short* ob = ctx + ((size_t)b * T_T + q0 + w * 32 + qc) * H_DIM
                         + hd * DHEAD;
    #pragma unroll
    for (int db = 0; db < 2; db++) {
        #pragma unroll
        for (int g = 0; g < 4; g++) {
            const int d0 = db * 32 + 8 * g + 4 * h;
            *(uint2*)(ob + d0) =
                make_uint2(pk_bf16(O[db][4 * g] * inv, O[db][4 * g + 1] * inv),
                           pk_bf16(O[db][4 * g + 2] * inv, O[db][4 * g + 3] * inv));
        }
    }
}

// ---------------------------------------------------- layernorm (both outputs)
__global__ __launch_bounds__(256) void k_layernorm(float* __restrict__ x,
                                                   const float* __restrict__ g0,
                                                   const float* __restrict__ b0,
                                                   const float* __restrict__ g1,
                                                   const float* __restrict__ b1)
{
    const int row = blockIdx.x;
    const float* g = row < 4096 ? g0 : g1;
    const float* bta = row < 4096 ? b0 : b1;
    float* p = x + (size_t)row * H_DIM;
    const int t = threadIdx.x;
    float vals[4];
    float s = 0.f, ss = 0.f;
    #pragma unroll
    for (int i = 0; i < 4; i++) {
        float v = p[t + 256 * i];
        vals[i] = v;
        s += v;
        ss += v * v;
    }
    #pragma unroll
    for (int o = 32; o > 0; o >>= 1) {
        s += __shfl_xor(s, o);
        ss += __shfl_xor(ss, o);
    }
    __shared__ float red[2][4];
    const int wid = t >> 6, lane = t & 63;
    if (lane == 0) { red[0][wid] = s; red[1][wid] = ss; }
    __syncthreads();
    s = red[0][0] + red[0][1] + red[0][2] + red[0][3];
    ss = red[1][0] + red[1][1] + red[1][2] + red[1][3];
    float mu = s * (1.0f / H_DIM);
    float var = ss * (1.0f / H_DIM) - mu * mu;
    float r = rsqrtf(var + 1e-12f);
    #pragma unroll
    for (int i = 0; i < 4; i++) {
        int idx = t + 256 * i;
        p[idx] = (vals[i] - mu) * r * g[idx] + bta[idx];
    }
}

// ---------------------------------------------------------------- launch
extern "C" void kernel_launch(void* const* d_in, const int* in_sizes, int n_in,
                              void* d_out, int out_size, void* d_ws, size_t ws_size,
                              hipStream_t stream) {
    const float* word = (const float*)d_in[0];
    const float* ent  = (const float*)d_in[1];
    const float* mask = (const float*)d_in[2];
    const float* qpos = (const float*)d_in[3];
    const float* Wq  = (const float*)d_in[4];  const float* bq  = (const float*)d_in[5];
    const float* Wk  = (const float*)d_in[6];  const float* bk  = (const float*)d_in[7];
    const float* Wv  = (const float*)d_in[8];  const float* bv  = (const float*)d_in[9];
    const float* Weq = (const float*)d_in[10]; const float* beq = (const float*)d_in[11];
    const float* Wek = (const float*)d_in[12]; const float* bek = (const float*)d_in[13];
    const float* Wev = (const float*)d_in[14]; const float* bev = (const float*)d_in[15];
    const float* Wo  = (const float*)d_in[16]; const float* bo  = (const float*)d_in[17];
    const float* Weo = (const float*)d_in[18]; const float* beo = (const float*)d_in[19];
    const float* ln_g  = (const float*)d_in[20]; const float* ln_b  = (const float*)d_in[21];
    const float* eln_g = (const float*)d_in[22]; const float* eln_b = (const float*)d_in[23];

    // Workspace (non-overlapping):
    char* ws = (char*)d_ws;
    unsigned short* word_bf = (unsigned short*)(ws);               //  0 .. 8 MB
    unsigned short* pe_bf   = (unsigned short*)(ws + 8388608);     //  8 .. 9 MB
    unsigned short* ent_bf  = (unsigned short*)(ws + 9437184);     //  9 ..10 MB
    float*          mask2   = (float*)(ws + 10466304);             // 18.4 KB pre-Wt
    unsigned short* Wt      = (unsigned short*)(ws + 10485760);    // 10 ..26 MB (8 x 2MB)
    unsigned short* qb      = (unsigned short*)(ws + 27262976);    // 26 ..35 MB
    unsigned short* kb      = (unsigned short*)(ws + 36700160);    // 35 ..44 MB
    unsigned short* vt      = (unsigned short*)(ws + 46137344);    // 44 ..53 MB
    unsigned short* ctx     = (unsigned short*)(ws + 55574528);    // 53 ..62 MB

    float* out_word = (float*)d_out;            // (4,1024,1024)
    float* out_ent  = out_word + 4194304;       // (4,128,1024)

    const size_t WSZ = (size_t)H_DIM * H_DIM;
    unsigned short* Wt_o  = Wt + 6 * WSZ;
    unsigned short* Wt_eo = Wt + 7 * WSZ;

    WPtrs wp = {{Wq, Wk, Wv, Weq, Wek, Wev, Wo, Weo}};
    k_prep2<<<dim3(12818), 256, 0, stream>>>(word, ent, qpos, mask,
                                             word_bf, pe_bf, ent_bf, mask2, wp, Wt);

    B6 bb = {{bq, bk, bv, beq, bek, bev}};
    O3p ow = {{qb, kb, vt}};
    k_proj<<<dim3(8, 72, 3), 256, 0, stream>>>(word_bf, pe_bf, ent_bf, Wt, bb, ow);

    k_attn<<<dim3(NHEAD * BATCH * 9), 256, 0, stream>>>(qb, kb, vt, mask2, ctx);

    k_gemm_out<<<dim3(576), 256, 0, stream>>>(ctx, Wt_o, Wt_eo, bo, beo,
                                              word, ent, out_word, out_ent);

    k_layernorm<<<dim3(4608), 256, 0, stream>>>(out_word, ln_g, ln_b, eln_g, eln_b);
}

// Round 14
// 249.961 us; speedup vs baseline: 1.0313x; 1.0313x over previous
//
#include <hip/hip_runtime.h>
#include <math.h>

#define H_DIM 1024
#define NHEAD 16
#define DHEAD 64
#define T_W 1024
#define T_E 128
#define T_T 1152
#define BATCH 4

typedef __attribute__((ext_vector_type(8))) short s8b;   // 8 bf16 (4 VGPRs)
typedef __attribute__((ext_vector_type(4))) short s4b;   // 4 bf16 (8 B)
typedef __attribute__((ext_vector_type(4))) float f32x4;

#define LOG2E 1.44269504088896f

__device__ __forceinline__ unsigned short f2bf(float f) {
    unsigned int u = __float_as_uint(f);
    u = (u + 0x7fffu + ((u >> 16) & 1u)) >> 16;   // RNE
    return (unsigned short)u;
}

__device__ __forceinline__ unsigned int pk_bf16(float a, float b) {
#if __has_builtin(__builtin_amdgcn_cvt_pk_bf16_f32)
    typedef __bf16 bf2 __attribute__((ext_vector_type(2)));
    bf2 r = __builtin_amdgcn_cvt_pk_bf16_f32(a, b);
    return __builtin_bit_cast(unsigned int, r);
#else
    return (unsigned int)f2bf(a) | ((unsigned int)f2bf(b) << 16);
#endif
}

__device__ __forceinline__ float exp2f_fast(float x) {
#if __has_builtin(__builtin_amdgcn_exp2f)
    return __builtin_amdgcn_exp2f(x);
#else
    return exp2f(x);
#endif
}

__device__ __forceinline__ void gld_lds16(const void* g, void* l) {
    __builtin_amdgcn_global_load_lds(
        (const __attribute__((address_space(1))) unsigned int*)g,
        (__attribute__((address_space(3))) unsigned int*)l, 16, 0, 0);
}

// ------------- fused prep: bf16 converts + mask prescale + 8 weight transposes
struct WPtrs { const float* w[8]; };
__global__ __launch_bounds__(256) void k_prep2(
    const float* __restrict__ word, const float* __restrict__ ent,
    const float* __restrict__ qp, const float* __restrict__ mask,
    unsigned short* __restrict__ word_bf, unsigned short* __restrict__ pe_bf,
    unsigned short* __restrict__ ent_bf, float* __restrict__ mask2,
    WPtrs ws, unsigned short* __restrict__ Wt)
{
    const int bid = blockIdx.x;
    if (bid < 4096) {
        int i = bid * 256 + threadIdx.x;
        float4 v = ((const float4*)word)[i];
        *(uint2*)(word_bf + (size_t)i * 4) =
            make_uint2(pk_bf16(v.x, v.y), pk_bf16(v.z, v.w));
    } else if (bid < 4608) {
        int i = (bid - 4096) * 256 + threadIdx.x;
        float4 a = ((const float4*)ent)[i];
        float4 b = ((const float4*)qp)[i];
        *(uint2*)(ent_bf + (size_t)i * 4) =
            make_uint2(pk_bf16(a.x, a.y), pk_bf16(a.z, a.w));
        *(uint2*)(pe_bf + (size_t)i * 4) =
            make_uint2(pk_bf16((a.x + b.x) * 0.5f, (a.y + b.y) * 0.5f),
                       pk_bf16((a.z + b.z) * 0.5f, (a.w + b.w) * 0.5f));
    } else if (bid < 4626) {
        int i = (bid - 4608) * 256 + threadIdx.x;
        if (i < BATCH * T_T) mask2[i] = mask[i] * LOG2E;
    } else {
        __shared__ float tile[32][33];
        const int id = bid - 4626;
        const int z = id >> 10, rem = id & 1023;
        const int kb = (rem >> 5) * 32, nb = (rem & 31) * 32;
        const float* src = ws.w[z];
        unsigned short* dst = Wt + (size_t)z * H_DIM * H_DIM;
        const int tx = threadIdx.x & 31, ty = threadIdx.x >> 5;
        #pragma unroll
        for (int i = 0; i < 4; i++)
            tile[ty * 4 + i][tx] = src[(size_t)(kb + ty * 4 + i) * H_DIM + nb + tx];
        __syncthreads();
        #pragma unroll
        for (int i = 0; i < 4; i++)
            dst[(size_t)(nb + ty * 4 + i) * H_DIM + kb + tx] =
                f2bf(tile[tx][ty * 4 + i]);
    }
}

struct B6 { const float* b[6]; };
struct O3p { void* o[3]; };

// =================== 64x128 BK=64 swizzled-LDS MFMA GEMM core ================
// LDS double-buffered, T4 counted-vmcnt loop: barrier(A) -> STAGE(t+1) ->
// vmcnt(6) waits only the 6 oldest loads (= tile t's), leaving tile t+1's 6
// in flight across the compute phase -> barrier(B) -> compute(t). Tail
// iteration drains with vmcnt(0).

#define STAGE_GEMM(k0, base)                                                     \
    {                                                                            \
        gld_lds16(gA + (k0), &sm[(base) + t * 8]);                               \
        gld_lds16(gA + (size_t)32 * H_DIM + (k0), &sm[(base) + 2048 + t * 8]);   \
        gld_lds16(gB + (k0), &sm[(base) + 4096 + t * 8]);                        \
        gld_lds16(gB + (size_t)32 * H_DIM + (k0), &sm[(base) + 6144 + t * 8]);   \
        gld_lds16(gB + (size_t)64 * H_DIM + (k0), &sm[(base) + 8192 + t * 8]);   \
        gld_lds16(gB + (size_t)96 * H_DIM + (k0), &sm[(base) + 10240 + t * 8]);  \
    }

#define GEMM_KLOOP                                                               \
    STAGE_GEMM(0, 0)                                                             \
    int base = 0;                                                                \
    for (int k0 = 0; k0 < H_DIM; k0 += 64) {                                     \
        __builtin_amdgcn_s_barrier();            /* (A) buf^1 reusable */        \
        if (k0 + 64 < H_DIM) {                                                   \
            STAGE_GEMM(k0 + 64, base ^ 12288)                                    \
            asm volatile("s_waitcnt vmcnt(6)" ::: "memory");                     \
        } else {                                                                 \
            asm volatile("s_waitcnt vmcnt(0)" ::: "memory");                     \
        }                                                                        \
        __builtin_amdgcn_s_barrier();            /* (B) tile-t LDS ready */      \
        __builtin_amdgcn_sched_barrier(0);                                       \
        _Pragma("unroll")                                                        \
        for (int kk = 0; kk < 2; kk++) {                                         \
            s8b af[2], bfr[4];                                                   \
            _Pragma("unroll")                                                    \
            for (int mt = 0; mt < 2; mt++) {                                     \
                const int r = wm * 32 + mt * 16 + col;                           \
                af[mt] = *(const s8b*)&sm[base + r * 64 +                        \
                                          (((kk * 4 + quad) ^ (r & 7)) * 8)];    \
            }                                                                    \
            _Pragma("unroll")                                                    \
            for (int nt = 0; nt < 4; nt++) {                                     \
                const int r = wn * 64 + nt * 16 + col;                           \
                bfr[nt] = *(const s8b*)&sm[base + 4096 + r * 64 +                \
                                           (((kk * 4 + quad) ^ (r & 7)) * 8)];   \
            }                                                                    \
            __builtin_amdgcn_s_setprio(1);                                       \
            _Pragma("unroll")                                                    \
            for (int mt = 0; mt < 2; mt++)                                       \
                _Pragma("unroll")                                                \
                for (int nt = 0; nt < 4; nt++)                                   \
                    acc[mt][nt] = __builtin_amdgcn_mfma_f32_16x16x32_bf16(       \
                        af[mt], bfr[nt], acc[mt][nt], 0, 0, 0);                  \
            __builtin_amdgcn_s_setprio(0);                                       \
        }                                                                        \
        base ^= 12288;                                                           \
    }

// ---------------------- QKV projections, word+entity in ONE launch
// grid (8, 72, 3): y<64 word (m0=y*64), else entity (m0=(y-64)*64); z: Q/K/V.
__global__ __launch_bounds__(256) void k_proj(
    const unsigned short* __restrict__ word_bf,
    const unsigned short* __restrict__ pe_bf,
    const unsigned short* __restrict__ ent_bf,
    const unsigned short* __restrict__ Wtbase, B6 biases, O3p outs)
{
    const int z = blockIdx.z;
    const bool isw = blockIdx.y < 64;
    const int Tseq = isw ? T_W : T_E;
    const int toff = isw ? 0 : T_W;
    const int m0 = (isw ? blockIdx.y : (blockIdx.y - 64)) * 64;
    const unsigned short* A = isw ? word_bf : (z == 2 ? ent_bf : pe_bf);
    const int wi = (isw ? 0 : 3) + z;
    const unsigned short* B = Wtbase + (size_t)wi * H_DIM * H_DIM;
    const float* bias = biases.b[wi];
    void* outp = outs.o[z];

    __shared__ unsigned short sm[24576];
    const int t = threadIdx.x;
    const int w = t >> 6, lane = t & 63;
    const int col = lane & 15, quad = lane >> 4;
    const int n0 = blockIdx.x * 128;
    const int wm = w & 1, wn = w >> 1;

    f32x4 acc[2][4] = {};

    const int rs = t >> 3;                       // staging row within pass
    const int gch = (t & 7) ^ (rs & 7);          // global chunk for this thread
    const unsigned short* gA = A + (size_t)(m0 + rs) * H_DIM + gch * 8;
    const unsigned short* gB = B + (size_t)(n0 + rs) * H_DIM + gch * 8;

    GEMM_KLOOP

    #pragma unroll
    for (int mt = 0; mt < 2; mt++) {
        const int mg = m0 + wm * 32 + mt * 16 + quad * 4;
        const int b = mg / Tseq, tt = toff + (mg % Tseq);
        #pragma unroll
        for (int nt = 0; nt < 4; nt++) {
            const int ng = n0 + wn * 64 + nt * 16 + col;
            f32x4 c = acc[mt][nt];
            const float bn = bias[ng];
            if (z < 2) {
                unsigned short* out = (unsigned short*)outp;
                #pragma unroll
                for (int r = 0; r < 4; r++)
                    out[((size_t)b * T_T + tt + r) * H_DIM + ng] = f2bf(c[r] + bn);
            } else {
                unsigned short* out = (unsigned short*)outp;
                *(uint2*)(out + ((size_t)b * H_DIM + ng) * T_T + tt) =
                    make_uint2(pk_bf16(c[0] + bn, c[1] + bn),
                               pk_bf16(c[2] + bn, c[3] + bn));
            }
        }
    }
}

// ---------------------- output GEMMs (word + entity), 576 blocks, 64x128 tile
__global__ __launch_bounds__(256) void k_gemm_out(
    const unsigned short* __restrict__ ctx,
    const unsigned short* __restrict__ Wt_o, const unsigned short* __restrict__ Wt_eo,
    const float* __restrict__ bo, const float* __restrict__ beo,
    const float* __restrict__ word, const float* __restrict__ ent,
    float* __restrict__ out_word, float* __restrict__ out_ent)
{
    const int blk = blockIdx.x;
    const bool is_word = blk < 512;
    const int lb = is_word ? blk : blk - 512;
    const int m0 = (lb >> 3) * 64, n0 = (lb & 7) * 128;
    const unsigned short* B = is_word ? Wt_o : Wt_eo;
    const float* bias = is_word ? bo : beo;
    const float* resid = is_word ? word : ent;
    float* out = is_word ? out_word : out_ent;
    const int Tseq = is_word ? T_W : T_E;
    const int toff = is_word ? 0 : T_W;

    __shared__ unsigned short sm[24576];
    const int t = threadIdx.x;
    const int w = t >> 6, lane = t & 63;
    const int col = lane & 15, quad = lane >> 4;
    const int wm = w & 1, wn = w >> 1;

    f32x4 acc[2][4] = {};

    const int rs = t >> 3;
    const int gch = (t & 7) ^ (rs & 7);
    // ctx row remap: 64-row tile stays within one batch (m0 mult of 64)
    const size_t arow = (size_t)(m0 / Tseq) * T_T + toff + (m0 % Tseq) + rs;
    const unsigned short* gA = ctx + arow * H_DIM + gch * 8;
    const unsigned short* gB = B + (size_t)(n0 + rs) * H_DIM + gch * 8;

    GEMM_KLOOP

    #pragma unroll
    for (int mt = 0; mt < 2; mt++) {
        const int mg = m0 + wm * 32 + mt * 16 + quad * 4;
        #pragma unroll
        for (int nt = 0; nt < 4; nt++) {
            const int ng = n0 + wn * 64 + nt * 16 + col;
            f32x4 c = acc[mt][nt];
            const float bn = bias[ng];
            #pragma unroll
            for (int r = 0; r < 4; r++) {
                const size_t idx = (size_t)(mg + r) * H_DIM + ng;
                out[idx] = c[r] + bn + resid[idx];
            }
        }
    }
}

// ------------------------------------------- cooperative S^T flash attention
// R10-verified best (51.2 us): 512 threads = 8 waves, 128 queries/block.
// Fixed-max softmax; XCD swizzle (T1, verified: FETCH 78.5 -> 13.9 MB).
// T4 counted-vmcnt loop: raw s_barrier pair per tile; prefetch for t+1 stays
// in flight across compute of t (vmcnt(6) waits only the 2 oldest = tile t's
// K/V). Mask loads hoisted before the prefetch (sched_barrier-pinned); their
// compiler wait is covered (issued at barrier(A), a full phase early).
// Structural lessons banked: R8 96q-rebalance -20%; R9 ones-MFMA -11%;
// R11 mask-LDS -5%; R13 32x32-MFMA -15% (2x bank conflicts, half TLP).
// This 2-barrier 8-wave structure is the verified local optimum.
__global__ __launch_bounds__(512) void k_attn(
    const unsigned short* __restrict__ q, const unsigned short* __restrict__ k,
    const unsigned short* __restrict__ vt, const float* __restrict__ mask2,
    unsigned short* __restrict__ ctx)
{
    const int tid = threadIdx.x;
    const int w = tid >> 6, lane = tid & 63;
    const int col = lane & 15, quad = lane >> 4;
    const int bid = blockIdx.x;
    const int bh = ((bid & 7) << 3) | ((bid >> 3) & 7);   // bijective over 576
    const int q0 = (bid >> 6) * 128 + w * 16;
    const int b = bh >> 4, h = bh & 15;

    __shared__ unsigned short sK[2][64 * 64];
    __shared__ unsigned short sV[2][64 * 64];
    __shared__ __align__(16) unsigned short sP[8][16 * 64];
    unsigned short* sp = &sP[w][0];

    const unsigned short* qp = q + ((size_t)b * T_T + q0) * H_DIM + h * DHEAD;
    const unsigned short* kp = k + (size_t)b * T_T * H_DIM + h * DHEAD;
    const unsigned short* vp = vt + ((size_t)b * H_DIM + h * DHEAD) * T_T;
    const float* mp = mask2 + (size_t)b * T_T;

    const s8b qf0 = *(const s8b*)(qp + (size_t)col * H_DIM + quad * 8);
    const s8b qf1 = *(const s8b*)(qp + (size_t)col * H_DIM + 32 + quad * 8);

    const int rA = tid >> 3;
    const int cA = (tid & 7) ^ (rA & 7);

    const float SC2 = 0.125f * LOG2E;

    f32x4 O[4] = {};
    float l_part = 0.f;

    #define PREFETCH(J0, BUF)                                                        \
        {                                                                            \
            gld_lds16(kp + (size_t)((J0) + rA) * H_DIM + cA * 8,                     \
                      &sK[BUF][0] + tid * 8);                                        \
            gld_lds16(vp + (size_t)rA * T_T + (J0) + cA * 8,                         \
                      &sV[BUF][0] + tid * 8);                                        \
        }

    PREFETCH(0, 0)
    for (int it = 0; it < 18; it++) {
        const int j0 = it * 64;
        // (A) all waves done computing tile it-1 -> buf (it+1)&1 reusable
        __builtin_amdgcn_s_barrier();
        // mask loads FIRST (older than prefetch in vmcnt order)
        float4 mrow[4];
        #pragma unroll
        for (int kt = 0; kt < 4; kt++)
            mrow[kt] = *(const float4*)(mp + j0 + kt * 16 + quad * 4);
        __builtin_amdgcn_sched_barrier(0);   // pin: mask before prefetch
        if (it < 17) {
            PREFETCH(j0 + 64, (it + 1) & 1)
            // outstanding: tile-it K/V (2, oldest) + mask (4) + prefetch (2)
            asm volatile("s_waitcnt vmcnt(6)" ::: "memory");
        } else {
            // outstanding: tile-17 K/V (2, oldest) + mask (4)
            asm volatile("s_waitcnt vmcnt(4)" ::: "memory");
        }
        // (B) every wave's tile-it loads have landed in LDS
        __builtin_amdgcn_s_barrier();
        __builtin_amdgcn_sched_barrier(0);

        const unsigned short* K0 = &sK[it & 1][0];
        const unsigned short* V0 = &sV[it & 1][0];

        float p[16];
        #pragma unroll
        for (int kt = 0; kt < 4; kt++) {
            const int rk = kt * 16 + col;
            const int csw = quad ^ (rk & 7);
            s8b k0f = *(const s8b*)(K0 + rk * 64 + csw * 8);
            s8b k1f = *(const s8b*)(K0 + rk * 64 + (csw ^ 4) * 8);
            f32x4 z = {0.f, 0.f, 0.f, 0.f};
            __builtin_amdgcn_s_setprio(1);
            z = __builtin_amdgcn_mfma_f32_16x16x32_bf16(k0f, qf0, z, 0, 0, 0);
            z = __builtin_amdgcn_mfma_f32_16x16x32_bf16(k1f, qf1, z, 0, 0, 0);
            __builtin_amdgcn_s_setprio(0);
            float mvv[4] = {mrow[kt].x, mrow[kt].y, mrow[kt].z, mrow[kt].w};
            #pragma unroll
            for (int r = 0; r < 4; r++) {
                float pe = exp2f_fast(fmaf(z[r], SC2, mvv[r]));
                p[kt * 4 + r] = pe;
                l_part += pe;
            }
        }

        #pragma unroll
        for (int kt = 0; kt < 4; kt++) {
            const int chunk = 2 * kt + (quad >> 1);
            *(uint2*)(sp + col * 64 + ((chunk ^ (col & 7)) * 8) + (quad & 1) * 4) =
                make_uint2(pk_bf16(p[4 * kt], p[4 * kt + 1]),
                           pk_bf16(p[4 * kt + 2], p[4 * kt + 3]));
        }
        const s8b p0 = *(const s8b*)(sp + col * 64 + ((quad ^ (col & 7)) * 8));
        const s8b p1 = *(const s8b*)(sp + col * 64 + (((4 + quad) ^ (col & 7)) * 8));

        __builtin_amdgcn_s_setprio(1);
        #pragma unroll
        for (int dt = 0; dt < 4; dt++) {
            const int rf = dt * 16 + col;
            const int csw = quad ^ (rf & 7);
            s8b v0 = *(const s8b*)(V0 + rf * 64 + csw * 8);
            s8b v1 = *(const s8b*)(V0 + rf * 64 + (csw ^ 4) * 8);
            O[dt] = __builtin_amdgcn_mfma_f32_16x16x32_bf16(v0, p0, O[dt], 0, 0, 0);
            O[dt] = __builtin_amdgcn_mfma_f32_16x16x32_bf16(v1, p1, O[dt], 0, 0, 0);
        }
        __builtin_amdgcn_s_setprio(0);
    }
    #undef PREFETCH

    float l_c = l_part;
    l_c += __shfl_xor(l_c, 16);
    l_c += __shfl_xor(l_c, 32);
    const float inv = 1.f / l_c;
    unsigned short* ob = ctx + ((size_t)b * T_T + q0 + col) * H_DIM + h * DHEAD;
    #pragma unroll
    for (int dt = 0; dt < 4; dt++) {
        *(uint2*)(ob + dt * 16 + quad * 4) =
            make_uint2(pk_bf16(O[dt][0] * inv, O[dt][1] * inv),
                       pk_bf16(O[dt][2] * inv, O[dt][3] * inv));
    }
}

// ---------------------------------------------------- layernorm (both outputs)
__global__ __launch_bounds__(256) void k_layernorm(float* __restrict__ x,
                                                   const float* __restrict__ g0,
                                                   const float* __restrict__ b0,
                                                   const float* __restrict__ g1,
                                                   const float* __restrict__ b1)
{
    const int row = blockIdx.x;
    const float* g = row < 4096 ? g0 : g1;
    const float* bta = row < 4096 ? b0 : b1;
    float* p = x + (size_t)row * H_DIM;
    const int t = threadIdx.x;
    float vals[4];
    float s = 0.f, ss = 0.f;
    #pragma unroll
    for (int i = 0; i < 4; i++) {
        float v = p[t + 256 * i];
        vals[i] = v;
        s += v;
        ss += v * v;
    }
    #pragma unroll
    for (int o = 32; o > 0; o >>= 1) {
        s += __shfl_xor(s, o);
        ss += __shfl_xor(ss, o);
    }
    __shared__ float red[2][4];
    const int wid = t >> 6, lane = t & 63;
    if (lane == 0) { red[0][wid] = s; red[1][wid] = ss; }
    __syncthreads();
    s = red[0][0] + red[0][1] + red[0][2] + red[0][3];
    ss = red[1][0] + red[1][1] + red[1][2] + red[1][3];
    float mu = s * (1.0f / H_DIM);
    float var = ss * (1.0f / H_DIM) - mu * mu;
    float r = rsqrtf(var + 1e-12f);
    #pragma unroll
    for (int i = 0; i < 4; i++) {
        int idx = t + 256 * i;
        p[idx] = (vals[i] - mu) * r * g[idx] + bta[idx];
    }
}

// ---------------------------------------------------------------- launch
extern "C" void kernel_launch(void* const* d_in, const int* in_sizes, int n_in,
                              void* d_out, int out_size, void* d_ws, size_t ws_size,
                              hipStream_t stream) {
    const float* word = (const float*)d_in[0];
    const float* ent  = (const float*)d_in[1];
    const float* mask = (const float*)d_in[2];
    const float* qpos = (const float*)d_in[3];
    const float* Wq  = (const float*)d_in[4];  const float* bq  = (const float*)d_in[5];
    const float* Wk  = (const float*)d_in[6];  const float* bk  = (const float*)d_in[7];
    const float* Wv  = (const float*)d_in[8];  const float* bv  = (const float*)d_in[9];
    const float* Weq = (const float*)d_in[10]; const float* beq = (const float*)d_in[11];
    const float* Wek = (const float*)d_in[12]; const float* bek = (const float*)d_in[13];
    const float* Wev = (const float*)d_in[14]; const float* bev = (const float*)d_in[15];
    const float* Wo  = (const float*)d_in[16]; const float* bo  = (const float*)d_in[17];
    const float* Weo = (const float*)d_in[18]; const float* beo = (const float*)d_in[19];
    const float* ln_g  = (const float*)d_in[20]; const float* ln_b  = (const float*)d_in[21];
    const float* eln_g = (const float*)d_in[22]; const float* eln_b = (const float*)d_in[23];

    // Workspace (non-overlapping):
    char* ws = (char*)d_ws;
    unsigned short* word_bf = (unsigned short*)(ws);               //  0 .. 8 MB
    unsigned short* pe_bf   = (unsigned short*)(ws + 8388608);     //  8 .. 9 MB
    unsigned short* ent_bf  = (unsigned short*)(ws + 9437184);     //  9 ..10 MB
    float*          mask2   = (float*)(ws + 10466304);             // 18.4 KB pre-Wt
    unsigned short* Wt      = (unsigned short*)(ws + 10485760);    // 10 ..26 MB (8 x 2MB)
    unsigned short* qb      = (unsigned short*)(ws + 27262976);    // 26 ..35 MB
    unsigned short* kb      = (unsigned short*)(ws + 36700160);    // 35 ..44 MB
    unsigned short* vt      = (unsigned short*)(ws + 46137344);    // 44 ..53 MB
    unsigned short* ctx     = (unsigned short*)(ws + 55574528);    // 53 ..62 MB

    float* out_word = (float*)d_out;            // (4,1024,1024)
    float* out_ent  = out_word + 4194304;       // (4,128,1024)

    const size_t WSZ = (size_t)H_DIM * H_DIM;
    unsigned short* Wt_o  = Wt + 6 * WSZ;
    unsigned short* Wt_eo = Wt + 7 * WSZ;

    WPtrs wp = {{Wq, Wk, Wv, Weq, Wek, Wev, Wo, Weo}};
    k_prep2<<<dim3(12818), 256, 0, stream>>>(word, ent, qpos, mask,
                                             word_bf, pe_bf, ent_bf, mask2, wp, Wt);

    B6 bb = {{bq, bk, bv, beq, bek, bev}};
    O3p ow = {{qb, kb, vt}};
    k_proj<<<dim3(8, 72, 3), 256, 0, stream>>>(word_bf, pe_bf, ent_bf, Wt, bb, ow);

    k_attn<<<dim3(NHEAD * BATCH * 9), 512, 0, stream>>>(qb, kb, vt, mask2, ctx);

    k_gemm_out<<<dim3(576), 256, 0, stream>>>(ctx, Wt_o, Wt_eo, bo, beo,
                                              word, ent, out_word, out_ent);

    k_layernorm<<<dim3(4608), 256, 0, stream>>>(out_word, ln_g, ln_b, eln_g, eln_b);
}